// Round 7
// baseline (2250.401 us; speedup 1.0000x reference)
//
#include <hip/hip_runtime.h>
#include <hip/hip_fp16.h>
#include <cstdint>

#define LATN 16
#define LONGN 12
#define PP 192          // LAT*LONG positions per n
#define CIN 128
#define CMID 128
#define EPSV 1e-5f
#define SPLIT 4         // blocks per n (channel split)
#define CHB 32          // channels per block
#define CST 196         // [row][p] tile stride (floats), 16B-aligned rows
#define GNN 4           // n's per block (dispatch-rate test)
#define UMAX 6          // scatter pipeline depth

typedef float v2f __attribute__((ext_vector_type(2)));

// ---------------- counting sort of scatter records by destination n ----------------

__global__ void count_kernel(const int* __restrict__ pidx, int* __restrict__ counts, int E) {
    int e = blockIdx.x * 256 + threadIdx.x;
    if (e >= E) return;
#pragma unroll
    for (int i = 0; i < 4; i++) {
        int v = pidx[i * E + e];
        int n = v / PP;
        atomicAdd(&counts[n], 1);
    }
}

// single block, 1024 threads, N <= 4096. counts may alias cur.
__global__ void scan_kernel(const int* __restrict__ counts, int* __restrict__ start,
                            int* __restrict__ cur, int N) {
    __shared__ int sdata[1024];
    int tid = threadIdx.x;
    int c[4];
    int s = 0;
#pragma unroll
    for (int j = 0; j < 4; j++) {
        int idx = tid * 4 + j;
        c[j] = (idx < N) ? counts[idx] : 0;
        s += c[j];
    }
    sdata[tid] = s;
    __syncthreads();
    for (int off = 1; off < 1024; off <<= 1) {
        int t = (tid >= off) ? sdata[tid - off] : 0;
        __syncthreads();
        sdata[tid] += t;
        __syncthreads();
    }
    int excl = sdata[tid] - s;
#pragma unroll
    for (int j = 0; j < 4; j++) {
        int idx = tid * 4 + j;
        if (idx < N) { start[idx] = excl; cur[idx] = excl; }
        excl += c[j];
    }
    if (tid == 1023) start[N] = sdata[1023];
}

// emit bucketed records: rec.x = src | (p<<18), rec.y = delta bits
__global__ void record_kernel(const int* __restrict__ pidx, const int* __restrict__ src_idx,
                              const float* __restrict__ delta, int* __restrict__ cur,
                              uint2* __restrict__ rec, int E) {
    int e = blockIdx.x * 256 + threadIdx.x;
    if (e >= E) return;
    int src = src_idx[e];
#pragma unroll
    for (int i = 0; i < 4; i++) {
        int v = pidx[i * E + e];
        int n = v / PP;
        int p = v - n * PP;
        int pos = atomicAdd(&cur[n], 1);
        rec[pos] = make_uint2((uint32_t)src | ((uint32_t)p << 18),
                              __float_as_uint(delta[i * E + e]));
    }
}

// weights -> f16x2 k-pairs, layout [i_pg][kp][o] (lane-coalesced over o)
__global__ void wt2_kernel(const float* __restrict__ w, uint32_t* __restrict__ wt2) {
    int id = blockIdx.x * 256 + threadIdx.x;
    if (id >= CIN * 6 * CMID) return;
    int o = id & 127;
    int kp = (id >> 7) % 6;
    int i = id / (128 * 6);
    float a = w[(o * 128 + i) * 12 + 2 * kp];
    float b = w[(o * 128 + i) * 12 + 2 * kp + 1];
    __half2 h = __floats2half2_rn(a, b);
    wt2[id] = *reinterpret_cast<uint32_t*>(&h);
}

// ---------------- fused: scatter->LDS tile, conv, silu, pool, groupnorm ----------------
// One block handles 32 channels (= 4 GroupNorm groups) of GNN consecutive n's.
// Tile layout: [row][p], row(c) = (c&7)*4 + (c>>3)  (bank-spread permutation)

__global__ __launch_bounds__(256, 6) void fused_kernel(
    const float* __restrict__ x, const uint2* __restrict__ rec,
    const int* __restrict__ start, const uint32_t* __restrict__ wt2,
    const float* __restrict__ conv_b, const float* __restrict__ gn_w,
    const float* __restrict__ gn_b, float* __restrict__ out) {
    __shared__ __align__(16) float tile[CHB * CST];     // 25088 B

    const int bid = blockIdx.x;
    const int ngrp = bid >> 2;
    const int b = bid & 3;
    const int tid = threadIdx.x;

    // scatter-phase thread mapping
    const int il = tid & 7;                 // lane within record: 4 channels each
    const int slot = tid >> 3;              // 0..31
    const int cbase = b * CHB + il * 4;     // global channel of this lane's float4
    const int row0 = ((il * 4 + 0) & 7) * 4 + ((il * 4 + 0) >> 3);
    const int row1 = ((il * 4 + 1) & 7) * 4 + ((il * 4 + 1) >> 3);
    const int row2 = ((il * 4 + 2) & 7) * 4 + ((il * 4 + 2) >> 3);
    const int row3 = ((il * 4 + 3) & 7) * 4 + ((il * 4 + 3) >> 3);

    // conv-phase thread mapping
    const int o_local = tid & 31;
    const int q = tid >> 5;                 // 0..7 = in-channel-within-group
    const int g_local = o_local >> 3;       // 0..3
    const int o = b * CHB + o_local;        // global out channel
    const int row = q * 4 + g_local;        // permuted tile row for channel g*8+q

    for (int i = 0; i < GNN; i++) {
        const int n = ngrp * GNN + i;
        __syncthreads();    // protect tile from previous iteration's epilogue readers

        // zero tile
        {
            float4 zz = {0.f, 0.f, 0.f, 0.f};
            float4* t4 = (float4*)tile;
#pragma unroll
            for (int r = 0; r < 7; r++) {
                int idx = tid + r * 256;
                if (idx < CHB * CST / 4) t4[idx] = zz;
            }
        }
        __syncthreads();

        // ---- scatter: 8 lanes/record (float4), UMAX-deep software pipeline ----
        {
            int b0 = start[n], b1 = start[n + 1];
            for (int it = b0 + slot; it < b1; it += 32 * UMAX) {
                uint2 rv[UMAX];
                float4 xv[UMAX];
                int idx[UMAX];
#pragma unroll
                for (int u = 0; u < UMAX; u++) {
                    idx[u] = it + u * 32;
                    if (idx[u] < b1) rv[u] = rec[idx[u]];
                }
#pragma unroll
                for (int u = 0; u < UMAX; u++) {
                    if (idx[u] < b1) {
                        int src = (int)(rv[u].x & 0x3FFFFu);
                        xv[u] = *(const float4*)(x + (size_t)src * CIN + cbase);
                    }
                }
#pragma unroll
                for (int u = 0; u < UMAX; u++) {
                    if (idx[u] < b1) {
                        float dl = __uint_as_float(rv[u].y);
                        int p = (int)(rv[u].x >> 18);
                        atomicAdd(&tile[row0 * CST + p], xv[u].x * dl);
                        atomicAdd(&tile[row1 * CST + p], xv[u].y * dl);
                        atomicAdd(&tile[row2 * CST + p], xv[u].z * dl);
                        atomicAdd(&tile[row3 * CST + p], xv[u].w * dl);
                    }
                }
            }
        }
        __syncthreads();

        // ---- grouped circular conv ----
        v2f acc2[6];
#pragma unroll
        for (int u = 0; u < 6; u++) acc2[u] = (v2f)(0.f);

        const float* tc = tile + row * CST;
        const uint32_t* wcol = wt2 + (size_t)(q * LATN) * 6 * CMID + o;

#pragma unroll
        for (int lat = 0; lat < LATN; lat++) {
            const float4 ra = *(const float4*)(tc + lat * LONGN);
            const float4 rb = *(const float4*)(tc + lat * LONGN + 4);
            const float4 rc = *(const float4*)(tc + lat * LONGN + 8);
            float r[12] = {ra.x, ra.y, ra.z, ra.w, rb.x, rb.y, rb.z, rb.w,
                           rc.x, rc.y, rc.z, rc.w};
            v2f rp[12];
#pragma unroll
            for (int j = 0; j < 12; j++) {
                rp[j].x = r[(j + 6) % 12];
                rp[j].y = r[(j + 7) % 12];
            }
            const uint32_t* wrow = wcol + (size_t)(lat * 6) * CMID;
#pragma unroll
            for (int kp = 0; kp < 6; kp++) {
                uint32_t wp = wrow[kp * CMID];
                __half2 h2 = *reinterpret_cast<__half2*>(&wp);
                float wlo = __half2float(h2.x);
                float whi = __half2float(h2.y);
                v2f wl2 = {wlo, wlo}, wh2 = {whi, whi};
#pragma unroll
                for (int u = 0; u < 6; u++) {
                    acc2[u] += wl2 * rp[(2 * kp + 2 * u) % 12];
                    acc2[u] += wh2 * rp[(2 * kp + 2 * u + 1) % 12];
                }
            }
        }
        __syncthreads();

        // ---- reduce partials across q (LDS), silu, pool, groupnorm ----
        float* pbuf = tile;                 // 8*12*32 = 3072 floats
#pragma unroll
        for (int u = 0; u < 6; u++) {
            pbuf[(q * 12 + 2 * u) * 32 + o_local] = acc2[u].x;
            pbuf[(q * 12 + 2 * u + 1) * 32 + o_local] = acc2[u].y;
        }
        __syncthreads();

        float* gbuf = tile + 8 * 12 * 32;   // 32 floats
        float sv = 0.f;
        if (tid < 32) {
            float bias = conv_b[b * CHB + tid];
#pragma unroll
            for (int t = 0; t < 12; t++) {
                float z = bias;
#pragma unroll
                for (int qq = 0; qq < 8; qq++) z += pbuf[(qq * 12 + t) * 32 + tid];
                sv += z / (1.f + __expf(-z));
            }
            sv *= (1.f / 12.f);
            gbuf[tid] = sv;
        }
        __syncthreads();
        if (tid < 32) {
            int gb = tid & ~7;
            float mu = 0.f, m2 = 0.f;
#pragma unroll
            for (int j = 0; j < 8; j++) {
                float v = gbuf[gb + j];
                mu += v;
                m2 += v * v;
            }
            mu *= 0.125f;
            float var = m2 * 0.125f - mu * mu;
            var = fmaxf(var, 0.f);
            float inv = rsqrtf(var + EPSV);
            int oc = b * CHB + tid;
            out[(size_t)n * CMID + oc] = (sv - mu) * inv * gn_w[oc] + gn_b[oc];
        }
    }
}

extern "C" void kernel_launch(void* const* d_in, const int* in_sizes, int n_in,
                              void* d_out, int out_size, void* d_ws, size_t ws_size,
                              hipStream_t stream) {
    const float* x = (const float*)d_in[0];
    const int* pidx = (const int*)d_in[2];
    const float* delta = (const float*)d_in[3];
    const int* src_idx = (const int*)d_in[4];
    const float* conv_w = (const float*)d_in[5];
    const float* conv_b = (const float*)d_in[6];
    const float* gn_w = (const float*)d_in[7];
    const float* gn_b = (const float*)d_in[8];
    float* out = (float*)d_out;

    int E = in_sizes[0] / CIN;          // 200000
    int N = out_size / CMID;            // 4096

    char* ws = (char*)d_ws;
    size_t off = 0;
    auto alloc = [&](size_t bytes) {
        size_t cur = off;
        off = (off + bytes + 255) & ~(size_t)255;
        return cur;
    };
    int* cur = (int*)(ws + alloc((size_t)N * 4));
    int* start = (int*)(ws + alloc((size_t)(N + 1) * 4));
    uint2* rec = (uint2*)(ws + alloc((size_t)4 * E * 8));
    uint32_t* wt2 = (uint32_t*)(ws + alloc((size_t)CIN * 6 * CMID * 4));

    hipMemsetAsync(cur, 0, (size_t)N * 4, stream);

    int gE = (E + 255) / 256;
    count_kernel<<<gE, 256, 0, stream>>>(pidx, cur, E);
    scan_kernel<<<1, 1024, 0, stream>>>(cur, start, cur, N);
    record_kernel<<<gE, 256, 0, stream>>>(pidx, src_idx, delta, cur, rec, E);
    wt2_kernel<<<(CIN * 6 * CMID + 255) / 256, 256, 0, stream>>>(conv_w, wt2);
    fused_kernel<<<(N / GNN) * SPLIT, 256, 0, stream>>>(x, rec, start, wt2, conv_b, gn_w, gn_b, out);
}

// Round 8
// 905.254 us; speedup vs baseline: 2.4859x; 2.4859x over previous
//
#include <hip/hip_runtime.h>
#include <hip/hip_fp16.h>
#include <cstdint>

#define LATN 16
#define LONGN 12
#define PP 192          // LAT*LONG positions per n
#define CIN 128
#define CMID 128
#define EPSV 1e-5f
#define SPLIT 4         // pass-A blocks per n (channel split)
#define CHB 32          // pass-A channels per block
#define CST 196         // pass-A [row][p] tile stride (floats)
#define UMAXA 4         // pass-A scatter pipeline depth (r6-proven, no spill)
#define CHBB 64         // pass-B channels per block
#define PSTR 194        // pass-B LDS half-stride (97 dwords: 2-way free)

typedef float v2f __attribute__((ext_vector_type(2)));

// ---------------- counting sort of scatter records by destination n ----------------

__global__ void count_kernel(const int* __restrict__ pidx, int* __restrict__ counts, int E) {
    int e = blockIdx.x * 256 + threadIdx.x;
    if (e >= E) return;
#pragma unroll
    for (int i = 0; i < 4; i++) {
        int v = pidx[i * E + e];
        int n = v / PP;
        atomicAdd(&counts[n], 1);
    }
}

__global__ void scan_kernel(const int* __restrict__ counts, int* __restrict__ start,
                            int* __restrict__ cur, int N) {
    __shared__ int sdata[1024];
    int tid = threadIdx.x;
    int c[4];
    int s = 0;
#pragma unroll
    for (int j = 0; j < 4; j++) {
        int idx = tid * 4 + j;
        c[j] = (idx < N) ? counts[idx] : 0;
        s += c[j];
    }
    sdata[tid] = s;
    __syncthreads();
    for (int off = 1; off < 1024; off <<= 1) {
        int t = (tid >= off) ? sdata[tid - off] : 0;
        __syncthreads();
        sdata[tid] += t;
        __syncthreads();
    }
    int excl = sdata[tid] - s;
#pragma unroll
    for (int j = 0; j < 4; j++) {
        int idx = tid * 4 + j;
        if (idx < N) { start[idx] = excl; cur[idx] = excl; }
        excl += c[j];
    }
    if (tid == 1023) start[N] = sdata[1023];
}

__global__ void record_kernel(const int* __restrict__ pidx, const int* __restrict__ src_idx,
                              const float* __restrict__ delta, int* __restrict__ cur,
                              uint2* __restrict__ rec, int E) {
    int e = blockIdx.x * 256 + threadIdx.x;
    if (e >= E) return;
    int src = src_idx[e];
#pragma unroll
    for (int i = 0; i < 4; i++) {
        int v = pidx[i * E + e];
        int n = v / PP;
        int p = v - n * PP;
        int pos = atomicAdd(&cur[n], 1);
        rec[pos] = make_uint2((uint32_t)src | ((uint32_t)p << 18),
                              __float_as_uint(delta[i * E + e]));
    }
}

// weights -> f16x2 k-pairs, layout [i][kp][o]
__global__ void wt2_kernel(const float* __restrict__ w, uint32_t* __restrict__ wt2) {
    int id = blockIdx.x * 256 + threadIdx.x;
    if (id >= CIN * 6 * CMID) return;
    int o = id & 127;
    int kp = (id >> 7) % 6;
    int i = id / (128 * 6);
    float a = w[(o * 128 + i) * 12 + 2 * kp];
    float b = w[(o * 128 + i) * 12 + 2 * kp + 1];
    __half2 h = __floats2half2_rn(a, b);
    wt2[id] = *reinterpret_cast<uint32_t*>(&h);
}

// ---------------- Pass A: scatter -> LDS tile -> f16 grid writeout ----------------
// Tile layout: [row][p], row(c) = (c&7)*4 + (c>>3); inverse c(r) = (r&3)*8 + (r>>2)

__global__ __launch_bounds__(256, 6) void scatter_kernel(
    const float* __restrict__ x, const uint2* __restrict__ rec,
    const int* __restrict__ start, __half* __restrict__ grid) {
    __shared__ __align__(16) float tile[CHB * CST];     // 25088 B

    int bid = blockIdx.x;
    int n = bid >> 2;
    int b = bid & 3;
    int tid = threadIdx.x;

    {
        float4 zz = {0.f, 0.f, 0.f, 0.f};
        float4* t4 = (float4*)tile;
#pragma unroll
        for (int r = 0; r < 7; r++) {
            int idx = tid + r * 256;
            if (idx < CHB * CST / 4) t4[idx] = zz;
        }
    }
    __syncthreads();

    int b0 = start[n], b1 = start[n + 1];
    {
        int il = tid & 7;
        int slot = tid >> 3;
        int cbase = b * CHB + il * 4;
        int row0 = ((il * 4 + 0) & 7) * 4 + ((il * 4 + 0) >> 3);
        int row1 = ((il * 4 + 1) & 7) * 4 + ((il * 4 + 1) >> 3);
        int row2 = ((il * 4 + 2) & 7) * 4 + ((il * 4 + 2) >> 3);
        int row3 = ((il * 4 + 3) & 7) * 4 + ((il * 4 + 3) >> 3);
        for (int it = b0 + slot; it < b1; it += 32 * UMAXA) {
            uint2 rv[UMAXA];
            float4 xv[UMAXA];
            int idx[UMAXA];
#pragma unroll
            for (int u = 0; u < UMAXA; u++) {
                idx[u] = it + u * 32;
                if (idx[u] < b1) rv[u] = rec[idx[u]];
            }
#pragma unroll
            for (int u = 0; u < UMAXA; u++) {
                if (idx[u] < b1) {
                    int src = (int)(rv[u].x & 0x3FFFFu);
                    xv[u] = *(const float4*)(x + (size_t)src * CIN + cbase);
                }
            }
#pragma unroll
            for (int u = 0; u < UMAXA; u++) {
                if (idx[u] < b1) {
                    float dl = __uint_as_float(rv[u].y);
                    int p = (int)(rv[u].x >> 18);
                    atomicAdd(&tile[row0 * CST + p], xv[u].x * dl);
                    atomicAdd(&tile[row1 * CST + p], xv[u].y * dl);
                    atomicAdd(&tile[row2 * CST + p], xv[u].z * dl);
                    atomicAdd(&tile[row3 * CST + p], xv[u].w * dl);
                }
            }
        }
    }
    __syncthreads();

    // writeout: f32 tile -> f16 grid [n][c][p]
    for (int idx = tid; idx < CHB * 48; idx += 256) {
        int r = idx / 48;
        int p4 = (idx - r * 48) * 4;
        int c = (r & 3) * 8 + (r >> 2);
        float4 v = *(const float4*)&tile[r * CST + p4];
        __half2 h0 = __floats2half2_rn(v.x, v.y);
        __half2 h1 = __floats2half2_rn(v.z, v.w);
        uint2 w2 = make_uint2(*reinterpret_cast<uint32_t*>(&h0),
                              *reinterpret_cast<uint32_t*>(&h1));
        *reinterpret_cast<uint2*>(grid + ((size_t)n * CIN + b * CHB + c) * PP + p4) = w2;
    }
}

// ---------------- Pass B: dense conv from f16 grid + silu/pool/groupnorm ----------------

__global__ __launch_bounds__(256, 4) void conv_kernel(
    const __half* __restrict__ grid, const uint32_t* __restrict__ wt2,
    const float* __restrict__ conv_b, const float* __restrict__ gn_w,
    const float* __restrict__ gn_b, float* __restrict__ out) {
    __shared__ __align__(16) float smem[CHBB * PSTR / 2];   // 24832 B
    __half* lt = (__half*)smem;                             // [64][PSTR]
    float* pbuf = smem;                                     // [4][64][12] (after conv)
    float* zbuf = smem + 4 * CHBB * LONGN;                  // [64][12]

    const int bid = blockIdx.x;
    const int n = bid >> 1;
    const int b = bid & 1;
    const int tid = threadIdx.x;

    // stage-in: 64 rows x 192 halfs
    for (int idx = tid; idx < CHBB * 48; idx += 256) {
        int r = idx / 48;
        int p4 = (idx - r * 48) * 4;
        uint2 v = *reinterpret_cast<const uint2*>(
            grid + ((size_t)n * CIN + b * CHBB + r) * PP + p4);
        *reinterpret_cast<uint32_t*>(lt + r * PSTR + p4) = v.x;
        *reinterpret_cast<uint32_t*>(lt + r * PSTR + p4 + 2) = v.y;
    }
    __syncthreads();

    const int o_local = tid & 63;
    const int w = tid >> 6;                 // 0..3 -> cl in {2w, 2w+1}
    const int g_local = o_local >> 3;
    const int o = b * CHBB + o_local;

    v2f acc2[6];
#pragma unroll
    for (int u = 0; u < 6; u++) acc2[u] = (v2f)(0.f);

#pragma unroll
    for (int e = 0; e < 2; e++) {
        const int cl = 2 * w + e;
        const __half* tcb = lt + (g_local * 8 + cl) * PSTR;
        const uint32_t* wcol = wt2 + (size_t)(cl * LATN) * 6 * CMID + o;
#pragma unroll
        for (int lat = 0; lat < LATN; lat++) {
            const __half* tc = tcb + lat * LONGN;
            float r[12];
#pragma unroll
            for (int m = 0; m < 6; m++) {
                __half2 h = *reinterpret_cast<const __half2*>(tc + 2 * m);
                r[2 * m] = __half2float(h.x);
                r[2 * m + 1] = __half2float(h.y);
            }
            v2f rp[12];
#pragma unroll
            for (int j = 0; j < 12; j++) {
                rp[j].x = r[(j + 6) % 12];
                rp[j].y = r[(j + 7) % 12];
            }
            const uint32_t* wrow = wcol + (size_t)(lat * 6) * CMID;
            uint32_t wp[6];
#pragma unroll
            for (int kp = 0; kp < 6; kp++) wp[kp] = wrow[kp * CMID];
#pragma unroll
            for (int kp = 0; kp < 6; kp++) {
                __half2 h2 = *reinterpret_cast<__half2*>(&wp[kp]);
                float wlo = __half2float(h2.x);
                float whi = __half2float(h2.y);
                v2f wl2 = {wlo, wlo}, wh2 = {whi, whi};
#pragma unroll
                for (int u = 0; u < 6; u++) {
                    acc2[u] += wl2 * rp[(2 * kp + 2 * u) % 12];
                    acc2[u] += wh2 * rp[(2 * kp + 2 * u + 1) % 12];
                }
            }
        }
    }
    __syncthreads();    // conv reads of lt done; pbuf may overwrite

    float* pw = pbuf + (w * CHBB + o_local) * LONGN;
    *(float4*)(pw + 0) = float4{acc2[0].x, acc2[0].y, acc2[1].x, acc2[1].y};
    *(float4*)(pw + 4) = float4{acc2[2].x, acc2[2].y, acc2[3].x, acc2[3].y};
    *(float4*)(pw + 8) = float4{acc2[4].x, acc2[4].y, acc2[5].x, acc2[5].y};
    __syncthreads();

    // stage1: z-sum + silu over 768 (o,t) pairs
    for (int idx = tid; idx < CHBB * LONGN; idx += 256) {
        int oo = idx / LONGN;
        float z = conv_b[b * CHBB + oo];
#pragma unroll
        for (int ww = 0; ww < 4; ww++) z += pbuf[(ww * CHBB) * LONGN + idx];
        zbuf[idx] = z / (1.f + __expf(-z));
    }
    __syncthreads();

    // stage2: pool + groupnorm (64 threads; groups = 8-lane slices)
    if (tid < CHBB) {
        const float* zr = zbuf + tid * LONGN;
        float4 za = *(const float4*)(zr);
        float4 zb = *(const float4*)(zr + 4);
        float4 zc = *(const float4*)(zr + 8);
        float sv = (za.x + za.y + za.z + za.w + zb.x + zb.y + zb.z + zb.w +
                    zc.x + zc.y + zc.z + zc.w) * (1.f / 12.f);
        float s1 = sv, s2 = sv * sv;
#pragma unroll
        for (int m = 1; m < 8; m <<= 1) {
            s1 += __shfl_xor(s1, m);
            s2 += __shfl_xor(s2, m);
        }
        float mu = s1 * 0.125f;
        float var = fmaxf(s2 * 0.125f - mu * mu, 0.f);
        float inv = rsqrtf(var + EPSV);
        int oc = b * CHBB + tid;
        out[(size_t)n * CMID + oc] = (sv - mu) * inv * gn_w[oc] + gn_b[oc];
    }
}

// ---------------- fallback: r6 single-pass fused kernel (ws too small) ----------------

__global__ __launch_bounds__(256, 6) void fused_kernel(
    const float* __restrict__ x, const uint2* __restrict__ rec,
    const int* __restrict__ start, const uint32_t* __restrict__ wt2,
    const float* __restrict__ conv_b, const float* __restrict__ gn_w,
    const float* __restrict__ gn_b, float* __restrict__ out) {
    __shared__ __align__(16) float tile[CHB * CST];

    int bid = blockIdx.x;
    int n = bid >> 2;
    int b = bid & 3;
    int tid = threadIdx.x;

    {
        float4 zz = {0.f, 0.f, 0.f, 0.f};
        float4* t4 = (float4*)tile;
#pragma unroll
        for (int r = 0; r < 7; r++) {
            int idx = tid + r * 256;
            if (idx < CHB * CST / 4) t4[idx] = zz;
        }
    }
    __syncthreads();

    int b0 = start[n], b1 = start[n + 1];
    {
        int il = tid & 7;
        int slot = tid >> 3;
        int cbase = b * CHB + il * 4;
        int row0 = ((il * 4 + 0) & 7) * 4 + ((il * 4 + 0) >> 3);
        int row1 = ((il * 4 + 1) & 7) * 4 + ((il * 4 + 1) >> 3);
        int row2 = ((il * 4 + 2) & 7) * 4 + ((il * 4 + 2) >> 3);
        int row3 = ((il * 4 + 3) & 7) * 4 + ((il * 4 + 3) >> 3);
        for (int it = b0 + slot; it < b1; it += 32 * UMAXA) {
            uint2 rv[UMAXA];
            float4 xv[UMAXA];
            int idx[UMAXA];
#pragma unroll
            for (int u = 0; u < UMAXA; u++) {
                idx[u] = it + u * 32;
                if (idx[u] < b1) rv[u] = rec[idx[u]];
            }
#pragma unroll
            for (int u = 0; u < UMAXA; u++) {
                if (idx[u] < b1) {
                    int src = (int)(rv[u].x & 0x3FFFFu);
                    xv[u] = *(const float4*)(x + (size_t)src * CIN + cbase);
                }
            }
#pragma unroll
            for (int u = 0; u < UMAXA; u++) {
                if (idx[u] < b1) {
                    float dl = __uint_as_float(rv[u].y);
                    int p = (int)(rv[u].x >> 18);
                    atomicAdd(&tile[row0 * CST + p], xv[u].x * dl);
                    atomicAdd(&tile[row1 * CST + p], xv[u].y * dl);
                    atomicAdd(&tile[row2 * CST + p], xv[u].z * dl);
                    atomicAdd(&tile[row3 * CST + p], xv[u].w * dl);
                }
            }
        }
    }
    __syncthreads();

    int o_local = tid & 31;
    int q = tid >> 5;
    int g_local = o_local >> 3;
    int o = b * CHB + o_local;
    int row = q * 4 + g_local;

    v2f acc2[6];
#pragma unroll
    for (int u = 0; u < 6; u++) acc2[u] = (v2f)(0.f);

    const float* tc = tile + row * CST;
    const uint32_t* wcol = wt2 + (size_t)(q * LATN) * 6 * CMID + o;

#pragma unroll
    for (int lat = 0; lat < LATN; lat++) {
        const float4 ra = *(const float4*)(tc + lat * LONGN);
        const float4 rb = *(const float4*)(tc + lat * LONGN + 4);
        const float4 rc = *(const float4*)(tc + lat * LONGN + 8);
        float r[12] = {ra.x, ra.y, ra.z, ra.w, rb.x, rb.y, rb.z, rb.w,
                       rc.x, rc.y, rc.z, rc.w};
        v2f rp[12];
#pragma unroll
        for (int j = 0; j < 12; j++) {
            rp[j].x = r[(j + 6) % 12];
            rp[j].y = r[(j + 7) % 12];
        }
        const uint32_t* wrow = wcol + (size_t)(lat * 6) * CMID;
#pragma unroll
        for (int kp = 0; kp < 6; kp++) {
            uint32_t wpv = wrow[kp * CMID];
            __half2 h2 = *reinterpret_cast<__half2*>(&wpv);
            float wlo = __half2float(h2.x);
            float whi = __half2float(h2.y);
            v2f wl2 = {wlo, wlo}, wh2 = {whi, whi};
#pragma unroll
            for (int u = 0; u < 6; u++) {
                acc2[u] += wl2 * rp[(2 * kp + 2 * u) % 12];
                acc2[u] += wh2 * rp[(2 * kp + 2 * u + 1) % 12];
            }
        }
    }
    __syncthreads();

    float* pbuf = tile;
#pragma unroll
    for (int u = 0; u < 6; u++) {
        pbuf[(q * 12 + 2 * u) * 32 + o_local] = acc2[u].x;
        pbuf[(q * 12 + 2 * u + 1) * 32 + o_local] = acc2[u].y;
    }
    __syncthreads();

    float* gbuf = tile + 8 * 12 * 32;
    float sv = 0.f;
    if (tid < 32) {
        float bias = conv_b[b * CHB + tid];
#pragma unroll
        for (int t = 0; t < 12; t++) {
            float z = bias;
#pragma unroll
            for (int qq = 0; qq < 8; qq++) z += pbuf[(qq * 12 + t) * 32 + tid];
            sv += z / (1.f + __expf(-z));
        }
        sv *= (1.f / 12.f);
        gbuf[tid] = sv;
    }
    __syncthreads();
    if (tid < 32) {
        int gb = tid & ~7;
        float mu = 0.f, m2 = 0.f;
#pragma unroll
        for (int j = 0; j < 8; j++) {
            float v = gbuf[gb + j];
            mu += v;
            m2 += v * v;
        }
        mu *= 0.125f;
        float var = m2 * 0.125f - mu * mu;
        var = fmaxf(var, 0.f);
        float inv = rsqrtf(var + EPSV);
        int oc = b * CHB + tid;
        out[(size_t)n * CMID + oc] = (sv - mu) * inv * gn_w[oc] + gn_b[oc];
    }
}

extern "C" void kernel_launch(void* const* d_in, const int* in_sizes, int n_in,
                              void* d_out, int out_size, void* d_ws, size_t ws_size,
                              hipStream_t stream) {
    const float* x = (const float*)d_in[0];
    const int* pidx = (const int*)d_in[2];
    const float* delta = (const float*)d_in[3];
    const int* src_idx = (const int*)d_in[4];
    const float* conv_w = (const float*)d_in[5];
    const float* conv_b = (const float*)d_in[6];
    const float* gn_w = (const float*)d_in[7];
    const float* gn_b = (const float*)d_in[8];
    float* out = (float*)d_out;

    int E = in_sizes[0] / CIN;          // 200000
    int N = out_size / CMID;            // 4096

    char* ws = (char*)d_ws;
    size_t off = 0;
    auto alloc = [&](size_t bytes) {
        size_t cur = off;
        off = (off + bytes + 255) & ~(size_t)255;
        return cur;
    };
    int* cur = (int*)(ws + alloc((size_t)N * 4));
    int* start = (int*)(ws + alloc((size_t)(N + 1) * 4));
    uint2* rec = (uint2*)(ws + alloc((size_t)4 * E * 8));
    uint32_t* wt2 = (uint32_t*)(ws + alloc((size_t)CIN * 6 * CMID * 4));
    size_t grid_off = alloc((size_t)N * CIN * PP * 2);
    __half* gridbuf = (__half*)(ws + grid_off);
    bool two_pass = (off <= ws_size);

    hipMemsetAsync(cur, 0, (size_t)N * 4, stream);

    int gE = (E + 255) / 256;
    count_kernel<<<gE, 256, 0, stream>>>(pidx, cur, E);
    scan_kernel<<<1, 1024, 0, stream>>>(cur, start, cur, N);
    record_kernel<<<gE, 256, 0, stream>>>(pidx, src_idx, delta, cur, rec, E);
    wt2_kernel<<<(CIN * 6 * CMID + 255) / 256, 256, 0, stream>>>(conv_w, wt2);

    if (two_pass) {
        scatter_kernel<<<N * SPLIT, 256, 0, stream>>>(x, rec, start, gridbuf);
        conv_kernel<<<N * 2, 256, 0, stream>>>(gridbuf, wt2, conv_b, gn_w, gn_b, out);
    } else {
        fused_kernel<<<N * SPLIT, 256, 0, stream>>>(x, rec, start, wt2, conv_b, gn_w, gn_b, out);
    }
}

// Round 9
// 380.419 us; speedup vs baseline: 5.9156x; 2.3796x over previous
//
#include <hip/hip_runtime.h>
#include <hip/hip_fp16.h>
#include <cstdint>

#define LATN 16
#define LONGN 12
#define PP 192          // LAT*LONG positions per n
#define NCELLS (4096 * PP)
#define CIN 128
#define CMID 128
#define EPSV 1e-5f
#define SPLIT 4         // blocks per n (channel split)
#define CHB 32          // channels per block
#define TST 36          // [p][c] tile stride (floats), 16B-aligned rows
#define UMAXA 4         // scatter pipeline depth

typedef float v2f __attribute__((ext_vector_type(2)));

// ---------------- counting sort of scatter records by destination CELL (n,p) ----------------
// proj_index IS the flat cell index v = n*192 + p.

__global__ void count2_kernel(const int* __restrict__ pidx, int* __restrict__ counts, int E) {
    int e = blockIdx.x * 256 + threadIdx.x;
    if (e >= E) return;
#pragma unroll
    for (int i = 0; i < 4; i++) {
        int v = pidx[i * E + e];
        atomicAdd(&counts[v], 1);
    }
}

// level-1 scan: 768 blocks x 1024, exclusive scan within block + block sums
__global__ void scan1_kernel(const int* __restrict__ cnt, int* __restrict__ startp,
                             int* __restrict__ bsum) {
    __shared__ int sd[1024];
    int t = threadIdx.x, b = blockIdx.x;
    int v = cnt[b * 1024 + t];
    sd[t] = v;
    __syncthreads();
    for (int off = 1; off < 1024; off <<= 1) {
        int x = (t >= off) ? sd[t - off] : 0;
        __syncthreads();
        sd[t] += x;
        __syncthreads();
    }
    startp[b * 1024 + t] = sd[t] - v;
    if (t == 1023) bsum[b] = sd[t];
}

// level-2: exclusive scan of 768 block sums (in place), grand total -> *grand
__global__ void scan2_kernel(int* __restrict__ bsum, int* __restrict__ grand, int nb) {
    __shared__ int sd[1024];
    int t = threadIdx.x;
    int v = (t < nb) ? bsum[t] : 0;
    sd[t] = v;
    __syncthreads();
    for (int off = 1; off < 1024; off <<= 1) {
        int x = (t >= off) ? sd[t - off] : 0;
        __syncthreads();
        sd[t] += x;
        __syncthreads();
    }
    if (t < nb) bsum[t] = sd[t] - v;
    if (t == 1023) *grand = sd[1023];
}

// add-back + produce cursor copy
__global__ void addback_kernel(int* __restrict__ startp, const int* __restrict__ bsum,
                               int* __restrict__ cur) {
    int v = blockIdx.x * 1024 + threadIdx.x;
    int s = startp[v] + bsum[blockIdx.x];
    startp[v] = s;
    cur[v] = s;
}

// emit cell-bucketed records: rec.x = src | (p<<18), rec.y = delta bits
__global__ void record_kernel(const int* __restrict__ pidx, const int* __restrict__ src_idx,
                              const float* __restrict__ delta, int* __restrict__ cur,
                              uint2* __restrict__ rec, int E) {
    int e = blockIdx.x * 256 + threadIdx.x;
    if (e >= E) return;
    int src = src_idx[e];
#pragma unroll
    for (int i = 0; i < 4; i++) {
        int v = pidx[i * E + e];
        int p = v - (v / PP) * PP;
        int pos = atomicAdd(&cur[v], 1);
        rec[pos] = make_uint2((uint32_t)src | ((uint32_t)p << 18),
                              __float_as_uint(delta[i * E + e]));
    }
}

// weights -> f16x2 k-pairs, layout [i][kp][o] (lane-coalesced over o)
__global__ void wt2_kernel(const float* __restrict__ w, uint32_t* __restrict__ wt2) {
    int id = blockIdx.x * 256 + threadIdx.x;
    if (id >= CIN * 6 * CMID) return;
    int o = id & 127;
    int kp = (id >> 7) % 6;
    int i = id / (128 * 6);
    float a = w[(o * 128 + i) * 12 + 2 * kp];
    float b = w[(o * 128 + i) * 12 + 2 * kp + 1];
    __half2 h = __floats2half2_rn(a, b);
    wt2[id] = *reinterpret_cast<uint32_t*>(&h);
}

// ---------------- fused: atomic-free scatter -> [p][c] tile, conv, silu, pool, gn ----------
// Block = (n, 32-channel split). 8-lane group (slot=tid>>3) owns p in [slot*6, slot*6+6);
// lane il owns channels il*4..il*4+3. Cell ownership exclusive per lane -> plain RMW.

__global__ __launch_bounds__(256, 5) void fused_kernel(
    const float* __restrict__ x, const uint2* __restrict__ rec,
    const int* __restrict__ start2, const uint32_t* __restrict__ wt2,
    const float* __restrict__ conv_b, const float* __restrict__ gn_w,
    const float* __restrict__ gn_b, float* __restrict__ out) {
    __shared__ __align__(16) float tile[PP * TST];      // 27648 B
    __shared__ int s2c[PP + 1];

    const int bid = blockIdx.x;
    const int n = bid >> 2;
    const int b = bid & 3;
    const int tid = threadIdx.x;

    // zero tile + stage cell offsets
    {
        float4 zz = {0.f, 0.f, 0.f, 0.f};
        float4* t4 = (float4*)tile;
        for (int idx = tid; idx < PP * TST / 4; idx += 256) t4[idx] = zz;
        for (int idx = tid; idx < PP + 1; idx += 256) s2c[idx] = start2[n * PP + idx];
    }
    __syncthreads();

    // ---- scatter: contiguous record range per group, 4-deep pipeline, NO atomics ----
    {
        const int il = tid & 7;
        const int slot = tid >> 3;
        const int cbase = b * CHB + il * 4;
        const int e1 = s2c[slot * 6 + 6];
        float* tbase = tile + il * 4;
        for (int e = s2c[slot * 6]; e < e1; e += UMAXA) {
            uint2 rv[UMAXA];
            float4 xv[UMAXA];
#pragma unroll
            for (int u = 0; u < UMAXA; u++) {
                if (e + u < e1) rv[u] = rec[e + u];
            }
#pragma unroll
            for (int u = 0; u < UMAXA; u++) {
                if (e + u < e1) {
                    int src = (int)(rv[u].x & 0x3FFFFu);
                    xv[u] = *(const float4*)(x + (size_t)src * CIN + cbase);
                }
            }
#pragma unroll
            for (int u = 0; u < UMAXA; u++) {
                if (e + u < e1) {
                    float dl = __uint_as_float(rv[u].y);
                    int p = (int)(rv[u].x >> 18);
                    float* tp = tbase + p * TST;
                    float4 t = *(const float4*)tp;
                    t.x += xv[u].x * dl;
                    t.y += xv[u].y * dl;
                    t.z += xv[u].z * dl;
                    t.w += xv[u].w * dl;
                    *(float4*)tp = t;
                }
            }
        }
    }
    __syncthreads();

    // ---- grouped circular conv: thread = (q = tid>>5, o_local = tid&31) ----
    const int o_local = tid & 31;
    const int q = tid >> 5;                 // 0..7 = in-channel-within-group
    const int g_local = o_local >> 3;       // 0..3
    const int o = b * CHB + o_local;        // global out channel
    const int ch = g_local * 8 + q;         // tile channel (within block)

    v2f acc2[6];
#pragma unroll
    for (int u = 0; u < 6; u++) acc2[u] = (v2f)(0.f);

    const uint32_t* wcol = wt2 + (size_t)(q * LATN) * 6 * CMID + o;

#pragma unroll
    for (int lat = 0; lat < LATN; lat++) {
        float r[12];
#pragma unroll
        for (int j = 0; j < 12; j++)
            r[j] = tile[(lat * LONGN + j) * TST + ch];
        v2f rp[12];
#pragma unroll
        for (int j = 0; j < 12; j++) {
            rp[j].x = r[(j + 6) % 12];
            rp[j].y = r[(j + 7) % 12];
        }
        const uint32_t* wrow = wcol + (size_t)(lat * 6) * CMID;
#pragma unroll
        for (int kp = 0; kp < 6; kp++) {
            uint32_t wp = wrow[kp * CMID];
            __half2 h2 = *reinterpret_cast<__half2*>(&wp);
            float wlo = __half2float(h2.x);
            float whi = __half2float(h2.y);
            v2f wl2 = {wlo, wlo}, wh2 = {whi, whi};
#pragma unroll
            for (int u = 0; u < 6; u++) {
                acc2[u] += wl2 * rp[(2 * kp + 2 * u) % 12];
                acc2[u] += wh2 * rp[(2 * kp + 2 * u + 1) % 12];
            }
        }
    }
    __syncthreads();

    // ---- reduce partials across q (LDS), silu, pool, groupnorm ----
    float* pbuf = tile;                     // 8*12*32 = 3072 floats
#pragma unroll
    for (int u = 0; u < 6; u++) {
        pbuf[(q * 12 + 2 * u) * 32 + o_local] = acc2[u].x;
        pbuf[(q * 12 + 2 * u + 1) * 32 + o_local] = acc2[u].y;
    }
    __syncthreads();

    float* gbuf = tile + 8 * 12 * 32;       // 32 floats
    float sv = 0.f;
    if (tid < 32) {
        float bias = conv_b[b * CHB + tid];
#pragma unroll
        for (int t = 0; t < 12; t++) {
            float z = bias;
#pragma unroll
            for (int qq = 0; qq < 8; qq++) z += pbuf[(qq * 12 + t) * 32 + tid];
            sv += z / (1.f + __expf(-z));
        }
        sv *= (1.f / 12.f);
        gbuf[tid] = sv;
    }
    __syncthreads();
    if (tid < 32) {
        int gb = tid & ~7;
        float mu = 0.f, m2 = 0.f;
#pragma unroll
        for (int j = 0; j < 8; j++) {
            float v = gbuf[gb + j];
            mu += v;
            m2 += v * v;
        }
        mu *= 0.125f;
        float var = m2 * 0.125f - mu * mu;
        var = fmaxf(var, 0.f);
        float inv = rsqrtf(var + EPSV);
        int oc = b * CHB + tid;
        out[(size_t)n * CMID + oc] = (sv - mu) * inv * gn_w[oc] + gn_b[oc];
    }
}

extern "C" void kernel_launch(void* const* d_in, const int* in_sizes, int n_in,
                              void* d_out, int out_size, void* d_ws, size_t ws_size,
                              hipStream_t stream) {
    const float* x = (const float*)d_in[0];
    const int* pidx = (const int*)d_in[2];
    const float* delta = (const float*)d_in[3];
    const int* src_idx = (const int*)d_in[4];
    const float* conv_w = (const float*)d_in[5];
    const float* conv_b = (const float*)d_in[6];
    const float* gn_w = (const float*)d_in[7];
    const float* gn_b = (const float*)d_in[8];
    float* out = (float*)d_out;

    int E = in_sizes[0] / CIN;          // 200000
    int N = out_size / CMID;            // 4096
    int ncells = N * PP;                // 786432

    char* ws = (char*)d_ws;
    size_t off = 0;
    auto alloc = [&](size_t bytes) {
        size_t cur = off;
        off = (off + bytes + 255) & ~(size_t)255;
        return cur;
    };
    int* count2 = (int*)(ws + alloc((size_t)ncells * 4));
    int* start2 = (int*)(ws + alloc((size_t)(ncells + 1) * 4));
    int* cur2   = (int*)(ws + alloc((size_t)ncells * 4));
    int* bsum   = (int*)(ws + alloc((size_t)1024 * 4));
    uint2* rec  = (uint2*)(ws + alloc((size_t)4 * E * 8));
    uint32_t* wt2 = (uint32_t*)(ws + alloc((size_t)CIN * 6 * CMID * 4));

    hipMemsetAsync(count2, 0, (size_t)ncells * 4, stream);

    int gE = (E + 255) / 256;
    int nb = ncells / 1024;             // 768
    count2_kernel<<<gE, 256, 0, stream>>>(pidx, count2, E);
    scan1_kernel<<<nb, 1024, 0, stream>>>(count2, start2, bsum);
    scan2_kernel<<<1, 1024, 0, stream>>>(bsum, start2 + ncells, nb);
    addback_kernel<<<nb, 1024, 0, stream>>>(start2, bsum, cur2);
    record_kernel<<<gE, 256, 0, stream>>>(pidx, src_idx, delta, cur2, rec, E);
    wt2_kernel<<<(CIN * 6 * CMID + 255) / 256, 256, 0, stream>>>(conv_w, wt2);
    fused_kernel<<<N * SPLIT, 256, 0, stream>>>(x, rec, start2, wt2, conv_b, gn_w, gn_b, out);
}